// Round 6
// baseline (215.337 us; speedup 1.0000x reference)
//
#include <hip/hip_runtime.h>
#include <hip/hip_bf16.h>
#include <stdint.h>

// MHA forward: N=2 L=2048 E=1024 H=16 D=64, fp32 in/out.
// Round 6: attention rewritten on 32x32x16 MFMA with in-register P (T12
// permlane32_swap), O accumulated transposed (O^T[d][q]); merge_convert does
// the LDS transpose. GEMMs/converts unchanged from round 5.
//
// Workspace (75,497,472 B peak):
//   [0,        2097152)   wo     (live until gemm<1>)
//   [2097152,  10485760)  xbf    -> after g0: l0/l1 overlays
//   [10485760, 16777216)  wqkv   (dead after g0)
//   [16777216, 41943040)  qkv    -> after attn: ocat (16.8M)
//   [41943040, 58720256)  O0T    [nh 32][d 64][q 2048] f32
//   [58720256, 75497472)  O1T

#define SEQ    2048
#define EMBED  1024
#define QS     3072      // qkv row stride ([Q|K|V])
#define MTOT   4096
#define SOFTMAX_C 0.04508422002778011f   // log2(e) / sqrt(1024)

using bf16x8 = __attribute__((ext_vector_type(8))) __bf16;
using f32x4  = __attribute__((ext_vector_type(4))) float;
using f32x16 = __attribute__((ext_vector_type(16))) float;
using u32x4  = __attribute__((ext_vector_type(4))) unsigned;
typedef int v2i __attribute__((ext_vector_type(2)));

__device__ __forceinline__ unsigned short f2bf(float f) {
  unsigned u = __builtin_bit_cast(unsigned, f);
  u += 0x7fffu + ((u >> 16) & 1u);          // RNE
  return (unsigned short)(u >> 16);
}
__device__ __forceinline__ float bf2f(unsigned short h) {
  return __builtin_bit_cast(float, (unsigned)h << 16);
}
__device__ __forceinline__ unsigned pk2(float a, float b) {
  return (unsigned)f2bf(a) | ((unsigned)f2bf(b) << 16);
}
// permlane32_swap: a' = {a[0:31], b[0:31]}, b' = {a[32:63], b[32:63]}
__device__ __forceinline__ void pl32swap(unsigned& a, unsigned& b) {
#if __has_builtin(__builtin_amdgcn_permlane32_swap)
  v2i r = __builtin_amdgcn_permlane32_swap((int)a, (int)b, false, false);
  a = (unsigned)r.x;
  b = (unsigned)r.y;
#else
  unsigned xa = (unsigned)__shfl_xor((int)a, 32, 64);
  unsigned xb = (unsigned)__shfl_xor((int)b, 32, 64);
  bool hi = (threadIdx.x & 63) >= 32;
  unsigned na = hi ? xb : a;
  unsigned nb = hi ? b : xa;
  a = na;
  b = nb;
#endif
}

__device__ __forceinline__ void gl_lds16(const void* g, void* l) {
  __builtin_amdgcn_global_load_lds(
      (const __attribute__((address_space(1))) unsigned int*)g,
      (__attribute__((address_space(3))) unsigned int*)l, 16, 0, 0);
}

// ---------------- fused conversion (hi-only) ----------------
__global__ void __launch_bounds__(256) convert_all(
    const float* __restrict__ x, const float* __restrict__ Wq,
    const float* __restrict__ Wk, const float* __restrict__ Wv,
    const float* __restrict__ Wo, unsigned short* __restrict__ xbf,
    unsigned short* __restrict__ wqkv, unsigned short* __restrict__ wo) {
  int b = blockIdx.x;
  int c4 = threadIdx.x << 2;
  const float* src;
  unsigned short* dst;
  if (b < 4096) {
    src = x + (size_t)b * EMBED;
    dst = xbf + (size_t)b * 1024;
  } else if (b < 7168) {
    int R = b - 4096;
    const float* W = (R < 1024) ? Wq : (R < 2048) ? Wk : Wv;
    src = W + (size_t)(R & 1023) * EMBED;
    dst = wqkv + (size_t)R * 1024;
  } else {
    int r = b - 7168;
    src = Wo + (size_t)r * EMBED;
    dst = wo + (size_t)r * 1024;
  }
  float4 v = *(const float4*)(src + c4);
  *(ushort4*)(dst + c4) = make_ushort4(f2bf(v.x), f2bf(v.y), f2bf(v.z), f2bf(v.w));
}

// ---------------- GEMM (unchanged, round-5 verified) ----------------
template <int MODE>   // 0: qkv (K=1024, bf16 out); 1: out-proj (K=2048, f32+bias)
__global__ void __launch_bounds__(256, 4) gemm_bt(
    const unsigned short* __restrict__ A, const unsigned short* __restrict__ B,
    void* __restrict__ Cout, const float* __restrict__ bias) {
  constexpr int BM   = (MODE == 0) ? 128 : 64;
  constexpr int LDA  = (MODE == 0) ? 1024 : 2048;
  constexpr int LDB  = 1024;
  constexpr int KTOT = (MODE == 0) ? 1024 : 2048;
  constexpr int NOUT = (MODE == 0) ? 3072 : 1024;
  constexpr int NBX  = NOUT / 128;
  constexpr int NWG  = (MTOT / BM) * NBX;
  constexpr int MI   = BM / 32;
  constexpr int AI   = BM / 32;

  __shared__ __align__(16) unsigned short Alds[BM * 64];
  __shared__ __align__(16) unsigned short Blds[128 * 64];
  const int tid = threadIdx.x;
  const int w = tid >> 6, lane = tid & 63;
  const int g = lane >> 4, l15 = lane & 15;

  int bid = blockIdx.y * NBX + blockIdx.x;
  int swz = (bid & 7) * (NWG / 8) + (bid >> 3);
  const int brow = (swz / NBX) * BM, bcol = (swz % NBX) * 128;
  const int wr = (w >> 1) * (BM / 2), wc = (w & 1) * 64;
  f32x4 acc[MI][4] = {};

  int rsA[AI], csA[AI], rsB[4], csB[4];
#pragma unroll
  for (int i = 0; i < AI; ++i) {
    int L = (i * 4 + w) * 1024 + lane * 16;
    int E = L ^ ((L >> 3) & 0x70);
    rsA[i] = E >> 7;
    csA[i] = (E & 127) >> 1;
  }
#pragma unroll
  for (int i = 0; i < 4; ++i) {
    int L = (i * 4 + w) * 1024 + lane * 16;
    int E = L ^ ((L >> 3) & 0x70);
    rsB[i] = E >> 7;
    csB[i] = (E & 127) >> 1;
  }

  for (int kt = 0; kt < KTOT / 64; ++kt) {
    const int k0 = kt << 6;
    const int k0b = k0 & 1023;
#pragma unroll
    for (int i = 0; i < AI; ++i)
      gl_lds16(A + (size_t)(brow + rsA[i]) * LDA + k0 + csA[i],
               (char*)Alds + (i * 4 + w) * 1024);
#pragma unroll
    for (int i = 0; i < 4; ++i)
      gl_lds16(B + (size_t)(bcol + rsB[i]) * LDB + k0b + csB[i],
               (char*)Blds + (i * 4 + w) * 1024);
    __syncthreads();
#pragma unroll
    for (int ks = 0; ks < 2; ++ks) {
      bf16x8 af[MI], bfr[4];
#pragma unroll
      for (int mi = 0; mi < MI; ++mi) {
        int row = wr + mi * 16 + l15;
        int byt = ((row << 7) + (ks << 6) + (g << 4)) ^ ((row & 7) << 4);
        af[mi] = *(const bf16x8*)((const char*)Alds + byt);
      }
#pragma unroll
      for (int ni = 0; ni < 4; ++ni) {
        int col = wc + ni * 16 + l15;
        int byt = ((col << 7) + (ks << 6) + (g << 4)) ^ ((col & 7) << 4);
        bfr[ni] = *(const bf16x8*)((const char*)Blds + byt);
      }
#pragma unroll
      for (int mi = 0; mi < MI; ++mi)
#pragma unroll
        for (int ni = 0; ni < 4; ++ni)
          acc[mi][ni] = __builtin_amdgcn_mfma_f32_16x16x32_bf16(af[mi], bfr[ni],
                                                                acc[mi][ni], 0, 0, 0);
    }
    __syncthreads();
  }
#pragma unroll
  for (int mi = 0; mi < MI; ++mi)
#pragma unroll
    for (int ni = 0; ni < 4; ++ni)
#pragma unroll
      for (int j = 0; j < 4; ++j) {
        int row = brow + wr + mi * 16 + g * 4 + j;
        int col = bcol + wc + ni * 16 + l15;
        if (MODE == 0) {
          ((unsigned short*)Cout)[(size_t)row * NOUT + col] = f2bf(acc[mi][ni][j]);
        } else {
          ((float*)Cout)[(size_t)row * NOUT + col] = acc[mi][ni][j] + bias[col];
        }
      }
}

// ---------------- attention v3: 32x32 MFMA, in-register P ----------------
// grid 1024 = n(2)*h(16)*qtile(16)*kvhalf(2), XCD-grouped. 4 waves x 32 q.
// Swapped QK^T: S^T = mfma32(K, Q): lane holds q=lane&31, k=(r&3)+8*(r>>2)+4*hi.
// P never touches LDS: exp2 -> pk2 pairs -> 2x permlane32_swap builds the PV
// B-frag {w0,w1,w2,w3} directly (desk-verified lane mapping).
// PV: O^T[d][q] = mfma32(V^T, P^T). V^T staged in LDS (XOR-swizzled both sides).
// T14: next K/V tile prefetched to regs before compute.
template <int B0, int SG>
__device__ __forceinline__ void proc_half(const f32x16& sf, const unsigned short* Vt_,
                                          int l31, int hi, float& lsum,
                                          f32x16& accO0, f32x16& accO1) {
  float e0 = __builtin_amdgcn_exp2f(sf[B0 + 0] * SOFTMAX_C);
  float e1 = __builtin_amdgcn_exp2f(sf[B0 + 1] * SOFTMAX_C);
  float e2 = __builtin_amdgcn_exp2f(sf[B0 + 2] * SOFTMAX_C);
  float e3 = __builtin_amdgcn_exp2f(sf[B0 + 3] * SOFTMAX_C);
  float e4 = __builtin_amdgcn_exp2f(sf[B0 + 4] * SOFTMAX_C);
  float e5 = __builtin_amdgcn_exp2f(sf[B0 + 5] * SOFTMAX_C);
  float e6 = __builtin_amdgcn_exp2f(sf[B0 + 6] * SOFTMAX_C);
  float e7 = __builtin_amdgcn_exp2f(sf[B0 + 7] * SOFTMAX_C);
  lsum += ((e0 + e1) + (e2 + e3)) + ((e4 + e5) + (e6 + e7));
  unsigned w0 = pk2(e0, e1), w1 = pk2(e2, e3), w2 = pk2(e4, e5), w3 = pk2(e6, e7);
  pl32swap(w0, w2);
  pl32swap(w1, w3);
  u32x4 fw = {w0, w1, w2, w3};
  bf16x8 pf = __builtin_bit_cast(bf16x8, fw);
  {
    int d = l31;
    int byt = (d * 144 + SG * 32 + hi * 16) ^ (((d >> 3) & 7) << 4);
    bf16x8 vf = *(const bf16x8*)((const char*)Vt_ + byt);
    accO0 = __builtin_amdgcn_mfma_f32_32x32x16_bf16(vf, pf, accO0, 0, 0, 0);
  }
  {
    int d = 32 + l31;
    int byt = (d * 144 + SG * 32 + hi * 16) ^ (((d >> 3) & 7) << 4);
    bf16x8 vf = *(const bf16x8*)((const char*)Vt_ + byt);
    accO1 = __builtin_amdgcn_mfma_f32_32x32x16_bf16(vf, pf, accO1, 0, 0, 0);
  }
}

__global__ void __launch_bounds__(256, 4) attn_kernel(
    const unsigned short* __restrict__ QKV, float* __restrict__ O0T,
    float* __restrict__ O1T, float* __restrict__ l0, float* __restrict__ l1) {
  __shared__ __align__(16) unsigned short Klds[64 * 72];   // [k][d], stride 72
  __shared__ __align__(16) unsigned short Vt[64 * 72];     // [d][k], stride 72, XOR-swz
  const int tid = threadIdx.x, w = tid >> 6, lane = tid & 63;
  const int l31 = lane & 31, hi = lane >> 5;
  const int b = blockIdx.x;
  const int swz = (b & 7) * 128 + (b >> 3);
  const int qt = swz & 15, h = (swz >> 4) & 15, n = (swz >> 8) & 1, half = (swz >> 9) & 1;
  const int nh = n * 16 + h;
  const int qw = qt * 128 + w * 32 + l31;   // this lane's q row
  const size_t rowbase = (size_t)n * SEQ;

  // Q B-frags: qf[s][j] = Q[qw][16s + 8hi + j]
  bf16x8 qf[4];
#pragma unroll
  for (int s = 0; s < 4; ++s)
    qf[s] = *(const bf16x8*)(QKV + (rowbase + qw) * QS + h * 64 + s * 16 + hi * 8);

  float lsum = 0.f;
  f32x16 accO0 = {}, accO1 = {};

  const int kr = tid >> 2, kc = (tid & 3) << 4;          // K staging map
  const int vr = (tid >> 3) << 1, vc = (tid & 7) << 3;   // V staging map (2 rows)
  const int vx = (tid & 7) << 4;                         // Vt write XOR bits

  const int kt0 = half * 16;
  uint4 ka, kb, va, vb;
  {
    const unsigned short* s = QKV + (rowbase + kt0 * 64 + kr) * QS + EMBED + h * 64 + kc;
    ka = *(const uint4*)s;
    kb = *(const uint4*)(s + 8);
    const unsigned short* sv = QKV + (rowbase + kt0 * 64 + vr) * QS + 2 * EMBED + h * 64 + vc;
    va = *(const uint4*)sv;
    vb = *(const uint4*)(sv + QS);
  }

  for (int kt = kt0; kt < kt0 + 16; ++kt) {
    // write staged regs -> LDS
    *(uint4*)&Klds[kr * 72 + kc] = ka;
    *(uint4*)&Klds[kr * 72 + kc + 8] = kb;
    {
      unsigned aw[4] = {va.x, va.y, va.z, va.w};
      unsigned bw[4] = {vb.x, vb.y, vb.z, vb.w};
      char* vbp = (char*)Vt;
#pragma unroll
      for (int i = 0; i < 4; ++i) {
        unsigned p0 = (aw[i] & 0xffffu) | (bw[i] << 16);
        unsigned p1 = (aw[i] >> 16) | (bw[i] & 0xffff0000u);
        *(unsigned*)(vbp + ((((vc + 2 * i) * 72 + vr) * 2) ^ vx)) = p0;
        *(unsigned*)(vbp + ((((vc + 2 * i + 1) * 72 + vr) * 2) ^ vx)) = p1;
      }
    }
    // T14: issue next-tile prefetch (hides HBM latency under compute)
    if (kt + 1 < kt0 + 16) {
      const unsigned short* s =
          QKV + (rowbase + (kt + 1) * 64 + kr) * QS + EMBED + h * 64 + kc;
      ka = *(const uint4*)s;
      kb = *(const uint4*)(s + 8);
      const unsigned short* sv =
          QKV + (rowbase + (kt + 1) * 64 + vr) * QS + 2 * EMBED + h * 64 + vc;
      va = *(const uint4*)sv;
      vb = *(const uint4*)(sv + QS);
    }
    __syncthreads();

    // k-tile 0 (k 0-31 of this KV block)
    f32x16 s0t = {};
#pragma unroll
    for (int s = 0; s < 4; ++s) {
      bf16x8 kf = *(const bf16x8*)((const char*)Klds + l31 * 144 + s * 32 + hi * 16);
      s0t = __builtin_amdgcn_mfma_f32_32x32x16_bf16(kf, qf[s], s0t, 0, 0, 0);
    }
    proc_half<0, 0>(s0t, Vt, l31, hi, lsum, accO0, accO1);
    proc_half<8, 1>(s0t, Vt, l31, hi, lsum, accO0, accO1);

    // k-tile 1 (k 32-63)
    f32x16 s1t = {};
#pragma unroll
    for (int s = 0; s < 4; ++s) {
      bf16x8 kf = *(const bf16x8*)((const char*)Klds + (32 + l31) * 144 + s * 32 + hi * 16);
      s1t = __builtin_amdgcn_mfma_f32_32x32x16_bf16(kf, qf[s], s1t, 0, 0, 0);
    }
    proc_half<0, 2>(s1t, Vt, l31, hi, lsum, accO0, accO1);
    proc_half<8, 3>(s1t, Vt, l31, hi, lsum, accO0, accO1);

    __syncthreads();
  }

  // epilogue: partial row-sums + transposed O store (coalesced along q)
  lsum += __shfl_xor(lsum, 32, 64);
  float* OT = half ? O1T : O0T;
  float* lp = half ? l1 : l0;
  if (hi == 0) lp[nh * SEQ + qw] = lsum;
  const size_t obase = (size_t)nh * 64 * SEQ + qw;
#pragma unroll
  for (int r = 0; r < 16; ++r) {
    int d0 = (r & 3) + 8 * (r >> 2) + 4 * hi;
    OT[obase + (size_t)d0 * SEQ] = accO0[r];
    OT[obase + (size_t)(d0 + 32) * SEQ] = accO1[r];
  }
}

// ---------------- merge partials (transpose) + convert to [hi|lo] ----------------
// grid 512 = nh(32) * qb(16 blocks of 128 q), 256 threads.
__global__ void __launch_bounds__(256) merge_convert(
    const float* __restrict__ O0T, const float* __restrict__ O1T,
    const float* __restrict__ l0, const float* __restrict__ l1,
    unsigned short* __restrict__ ocat) {
  __shared__ float ftile[64][132];
  __shared__ float llds[128];
  const int b = blockIdx.x;
  const int nh = b >> 4, qb = b & 15;
  const int t = threadIdx.x;
  if (t < 128) {
    int q = qb * 128 + t;
    llds[t] = 1.0f / (l0[nh * SEQ + q] + l1[nh * SEQ + q]);
  }
  const size_t base = (size_t)nh * 64 * SEQ + qb * 128;
#pragma unroll
  for (int p = 0; p < 8; ++p) {
    int d = (t >> 5) + p * 8;
    int qq = (t & 31) * 4;
    float4 a = *(const float4*)(O0T + base + (size_t)d * SEQ + qq);
    float4 c = *(const float4*)(O1T + base + (size_t)d * SEQ + qq);
    float4 s4 = {a.x + c.x, a.y + c.y, a.z + c.z, a.w + c.w};
    *(float4*)&ftile[d][qq] = s4;
  }
  __syncthreads();
  const int q = t >> 1, sect = t & 1;
  const float linv = llds[q];
  const int n = nh >> 4, h = nh & 15;
  unsigned short* orow =
      ocat + (size_t)(n * SEQ + qb * 128 + q) * 2048 + h * 64 + sect * 32;
#pragma unroll
  for (int i = 0; i < 32; i += 4) {
    unsigned short hx[4], lx[4];
#pragma unroll
    for (int k = 0; k < 4; ++k) {
      float v = ftile[sect * 32 + i + k][q] * linv;
      hx[k] = f2bf(v);
      lx[k] = f2bf(v - bf2f(hx[k]));
    }
    *(ushort4*)(orow + i) = make_ushort4(hx[0], hx[1], hx[2], hx[3]);
    *(ushort4*)(orow + 1024 + i) = make_ushort4(lx[0], lx[1], lx[2], lx[3]);
  }
}

// ---------------- launch ----------------
extern "C" void kernel_launch(void* const* d_in, const int* in_sizes, int n_in,
                              void* d_out, int out_size, void* d_ws, size_t ws_size,
                              hipStream_t stream) {
  const float* x  = (const float*)d_in[0];
  const float* Wq = (const float*)d_in[1];
  const float* Wk = (const float*)d_in[2];
  const float* Wv = (const float*)d_in[3];
  const float* Wo = (const float*)d_in[4];
  const float* bo = (const float*)d_in[5];

  char* ws = (char*)d_ws;
  unsigned short* wo    = (unsigned short*)(ws);              // 1024x1024 (2M)
  unsigned short* xbf   = (unsigned short*)(ws + 2097152);    // 4096x1024 (8.4M)
  unsigned short* wqkv  = (unsigned short*)(ws + 10485760);   // 3072x1024 (6.3M)
  unsigned short* qkv   = (unsigned short*)(ws + 16777216);   // 4096x3072 (25.2M)
  float* l0p = (float*)(ws + 2097152);                        // over xbf (dead), 256K
  float* l1p = (float*)(ws + 2359296);                        // 256K
  float* O0T = (float*)(ws + 41943040);                       // 16.8M
  float* O1T = (float*)(ws + 58720256);                       // 16.8M
  unsigned short* ocat = qkv;                                 // over qkv (dead), 16.8M

  convert_all<<<8192, 256, 0, stream>>>(x, Wq, Wk, Wv, Wo, xbf, wqkv, wo);

  gemm_bt<0><<<dim3(3072 / 128, MTOT / 128), 256, 0, stream>>>(xbf, wqkv, qkv, nullptr);

  attn_kernel<<<1024, 256, 0, stream>>>(qkv, O0T, O1T, l0p, l1p);
  merge_convert<<<512, 256, 0, stream>>>(O0T, O1T, l0p, l1p, ocat);

  gemm_bt<1><<<dim3(1024 / 128, MTOT / 64), 256, 0, stream>>>(ocat, wo, d_out, bo);
}